// Round 1
// baseline (946.573 us; speedup 1.0000x reference)
//
#include <hip/hip_runtime.h>
#include <stdint.h>

#define T_TOK 8192
#define DM 1024
#define HID 4096
#define NE 8
#define RP_MAX 17408   // 16384 + 8*128 worst-case padded rows
#define MTILES 136     // RP_MAX / 128

typedef unsigned short u16;
typedef __attribute__((ext_vector_type(4))) float f32x4;
typedef __attribute__((ext_vector_type(8))) __bf16 bf16x8;

#define GLB(p) ((const __attribute__((address_space(1))) unsigned int*)(p))
#define LDSP(p) ((__attribute__((address_space(3))) unsigned int*)(p))

__device__ __forceinline__ u16 f2bf(float f) {
    union { float f; unsigned u; } c; c.f = f;
    unsigned r = (c.u + 0x7FFFu + ((c.u >> 16) & 1u)) >> 16;
    return (u16)r;
}

// ---------- 0: zero counters ----------
__global__ void k_zero(int* counts, int* cursors) {
    if (threadIdx.x < NE) { counts[threadIdx.x] = 0; cursors[threadIdx.x] = 0; }
}

// ---------- 1: gating (one wave per token, fp32) ----------
__global__ __launch_bounds__(256) void k_gate(const float* __restrict__ x,
        const float* __restrict__ gw, const float* __restrict__ gb,
        int* __restrict__ tok_e, float* __restrict__ tok_w, int* __restrict__ counts) {
    int t = blockIdx.x * 4 + (threadIdx.x >> 6);
    int lane = threadIdx.x & 63;
    const float* xr = x + (size_t)t * DM;
    float a0=0,a1=0,a2=0,a3=0,a4=0,a5=0,a6=0,a7=0;
    for (int d = lane; d < DM; d += 64) {
        float xv = xr[d];
        const float4* g = (const float4*)(gw + (size_t)d * NE);
        float4 g0 = g[0], g1 = g[1];
        a0 += xv*g0.x; a1 += xv*g0.y; a2 += xv*g0.z; a3 += xv*g0.w;
        a4 += xv*g1.x; a5 += xv*g1.y; a6 += xv*g1.z; a7 += xv*g1.w;
    }
    #pragma unroll
    for (int off = 32; off; off >>= 1) {
        a0 += __shfl_xor(a0, off); a1 += __shfl_xor(a1, off);
        a2 += __shfl_xor(a2, off); a3 += __shfl_xor(a3, off);
        a4 += __shfl_xor(a4, off); a5 += __shfl_xor(a5, off);
        a6 += __shfl_xor(a6, off); a7 += __shfl_xor(a7, off);
    }
    if (lane == 0) {
        float l[8] = {a0+gb[0],a1+gb[1],a2+gb[2],a3+gb[3],a4+gb[4],a5+gb[5],a6+gb[6],a7+gb[7]};
        int e0 = 0;
        #pragma unroll
        for (int e = 1; e < 8; ++e) if (l[e] > l[e0]) e0 = e;
        int e1 = (e0 == 0) ? 1 : 0;
        #pragma unroll
        for (int e = 0; e < 8; ++e) if (e != e0 && l[e] > l[e1]) e1 = e;
        // top-2 renormalized softmax: full denominator cancels
        float p1 = expf(l[e1] - l[e0]);
        float inv = 1.f / (1.f + p1);
        tok_e[2*t] = e0; tok_e[2*t+1] = e1;
        tok_w[2*t] = inv; tok_w[2*t+1] = p1 * inv;
        atomicAdd(&counts[e0], 1);
        atomicAdd(&counts[e1], 1);
    }
}

// ---------- 2: padded prefix + tile->expert map ----------
__global__ void k_scan(const int* __restrict__ counts, int* __restrict__ pad_off,
                       int* __restrict__ tile_expert, int* __restrict__ row_token) {
    __shared__ int off[NE + 1];
    if (threadIdx.x == 0) {
        int o = 0;
        for (int e = 0; e < NE; ++e) { off[e] = o; pad_off[e] = o; o += ((counts[e] + 127) >> 7) << 7; }
        off[NE] = o; pad_off[NE] = o;
    }
    __syncthreads();
    for (int i = threadIdx.x; i < MTILES; i += blockDim.x) {
        int ex = -1, base = i * 128;
        #pragma unroll
        for (int e = 0; e < NE; ++e) if (base >= off[e] && base < off[e+1]) ex = e;
        tile_expert[i] = ex;
    }
    for (int i = threadIdx.x; i < RP_MAX; i += blockDim.x) row_token[i] = -1;
}

// ---------- 3: assign rows ----------
__global__ __launch_bounds__(256) void k_assign(const int* __restrict__ tok_e, const float* __restrict__ tok_w,
        const int* __restrict__ pad_off, int* __restrict__ cursors,
        int* __restrict__ row_token, float* __restrict__ row_weight, int* __restrict__ token_rows) {
    int t = blockIdx.x * 256 + threadIdx.x;
    if (t >= T_TOK) return;
    #pragma unroll
    for (int k = 0; k < 2; ++k) {
        int e = tok_e[2*t+k];
        int pos = atomicAdd(&cursors[e], 1);
        int r = pad_off[e] + pos;
        row_token[r] = t;
        row_weight[r] = tok_w[2*t+k];
        token_rows[2*t+k] = r;
    }
}

// ---------- 4: x fp32 -> bf16 ----------
__global__ __launch_bounds__(256) void k_convx(const float* __restrict__ x, u16* __restrict__ xb) {
    size_t i = ((size_t)blockIdx.x * 256 + threadIdx.x) * 8;
    const float4* p = (const float4*)(x + i);
    float4 v0 = p[0], v1 = p[1];
    uint4 o;
    o.x = f2bf(v0.x) | ((unsigned)f2bf(v0.y) << 16);
    o.y = f2bf(v0.z) | ((unsigned)f2bf(v0.w) << 16);
    o.z = f2bf(v1.x) | ((unsigned)f2bf(v1.y) << 16);
    o.w = f2bf(v1.z) | ((unsigned)f2bf(v1.w) << 16);
    *(uint4*)(xb + i) = o;
}

// ---------- 5: weight transpose+convert: [E][R][C] f32 -> [E][C][R] bf16 ----------
template<int R, int C>
__global__ __launch_bounds__(256) void k_transpose(const float* __restrict__ in, u16* __restrict__ out) {
    __shared__ u16 lds[64][65];
    const int TC = C / 64;
    const int tiles = (R / 64) * TC;
    int e = blockIdx.x / tiles;
    int rem = blockIdx.x % tiles;
    int rt = rem / TC, ct = rem % TC;
    const float* src = in + (size_t)e * R * C;
    u16* dst = out + (size_t)e * R * C;
    int rl = threadIdx.x >> 4;
    int cl = (threadIdx.x & 15) * 4;
    #pragma unroll
    for (int i = 0; i < 4; ++i) {
        int r = rl + i * 16;
        float4 v = *(const float4*)&src[(size_t)(rt*64 + r) * C + ct*64 + cl];
        lds[r][cl+0] = f2bf(v.x); lds[r][cl+1] = f2bf(v.y);
        lds[r][cl+2] = f2bf(v.z); lds[r][cl+3] = f2bf(v.w);
    }
    __syncthreads();
    #pragma unroll
    for (int i = 0; i < 4; ++i) {
        int ro = rl + i * 16;
        ushort4 o;
        o.x = lds[cl+0][ro]; o.y = lds[cl+1][ro];
        o.z = lds[cl+2][ro]; o.w = lds[cl+3][ro];
        *(ushort4*)&dst[(size_t)(ct*64 + ro) * R + rt*64 + cl] = o;
    }
}

// ---------- 6: MoE GEMM (128x128 tile, BK=64, 4 waves, 16x16x32 bf16 MFMA) ----------
template<int N, int K, bool GATHER, bool SILU>
__global__ __launch_bounds__(256) void k_gemm(
    const u16* __restrict__ Asrc, const u16* __restrict__ Bw,
    const float* __restrict__ bias, void* __restrict__ Out,
    const int* __restrict__ row_token, const int* __restrict__ tile_expert)
{
    int bn = blockIdx.x, bm = blockIdx.y;
    int e = tile_expert[bm];
    if (e < 0) return;
    int tid = threadIdx.x, wid = tid >> 6, lane = tid & 63;

    __shared__ u16 Al[128 * 64];
    __shared__ u16 Bl[128 * 64];

    // staging source pointers: inst i of wave wid covers rows (wid*4+i)*8 + (lane>>3),
    // 16B per lane at k-offset (lane&7)*8; LDS dest is linear (uniform base + lane*16)
    const u16* ap[4];
    const u16* bp[4];
    #pragma unroll
    for (int i = 0; i < 4; ++i) {
        int row = (wid * 4 + i) * 8 + (lane >> 3);
        size_t arow;
        if (GATHER) {
            int tk = row_token[bm * 128 + row];
            if (tk < 0) tk = 0;              // pad rows compute duplicate of token 0 (ignored)
            arow = (size_t)tk * K;
        } else {
            arow = (size_t)(bm * 128 + row) * K;
        }
        ap[i] = Asrc + arow + (lane & 7) * 8;
        bp[i] = Bw + (size_t)e * N * K + (size_t)(bn * 128 + row) * K + (lane & 7) * 8;
    }

    f32x4 acc[4][4];
    #pragma unroll
    for (int i = 0; i < 4; ++i)
        #pragma unroll
        for (int j = 0; j < 4; ++j) acc[i][j] = f32x4{0.f, 0.f, 0.f, 0.f};

    int wr = wid >> 1, wc = wid & 1;

    for (int kt = 0; kt < K / 64; ++kt) {
        #pragma unroll
        for (int i = 0; i < 4; ++i) {
            __builtin_amdgcn_global_load_lds(GLB(ap[i] + kt * 64), LDSP(&Al[(wid*4+i)*512]), 16, 0, 0);
            __builtin_amdgcn_global_load_lds(GLB(bp[i] + kt * 64), LDSP(&Bl[(wid*4+i)*512]), 16, 0, 0);
        }
        asm volatile("s_waitcnt vmcnt(0)" ::: "memory");
        __syncthreads();
        #pragma unroll
        for (int s = 0; s < 2; ++s) {
            bf16x8 af[4], bfr[4];
            #pragma unroll
            for (int i = 0; i < 4; ++i)
                af[i] = *(const bf16x8*)&Al[(wr*64 + i*16 + (lane & 15)) * 64 + s*32 + (lane >> 4) * 8];
            #pragma unroll
            for (int j = 0; j < 4; ++j)
                bfr[j] = *(const bf16x8*)&Bl[(wc*64 + j*16 + (lane & 15)) * 64 + s*32 + (lane >> 4) * 8];
            #pragma unroll
            for (int i = 0; i < 4; ++i)
                #pragma unroll
                for (int j = 0; j < 4; ++j)
                    acc[i][j] = __builtin_amdgcn_mfma_f32_16x16x32_bf16(af[i], bfr[j], acc[i][j], 0, 0, 0);
        }
        __syncthreads();
    }

    // epilogue: C row = (lane>>4)*4 + reg, col = lane&15 (verified gfx950 C/D layout)
    int rbase = bm * 128 + wr * 64 + (lane >> 4) * 4;
    int cbase = bn * 128 + wc * 64 + (lane & 15);
    #pragma unroll
    for (int j = 0; j < 4; ++j) {
        int col = cbase + j * 16;
        float bv = bias[e * N + col];
        #pragma unroll
        for (int i = 0; i < 4; ++i) {
            #pragma unroll
            for (int r = 0; r < 4; ++r) {
                int row = rbase + i * 16 + r;
                float v = acc[i][j][r] + bv;
                if (SILU) {
                    v = v / (1.f + __expf(-v));
                    ((u16*)Out)[(size_t)row * N + col] = f2bf(v);
                } else {
                    ((float*)Out)[(size_t)row * N + col] = v;
                }
            }
        }
    }
}

// ---------- 7: combine (one block per token, float4) ----------
__global__ __launch_bounds__(256) void k_combine(const float* __restrict__ ybuf,
        const int* __restrict__ token_rows, const float* __restrict__ row_weight,
        float* __restrict__ out) {
    int t = blockIdx.x;
    int d = threadIdx.x * 4;
    int r0 = token_rows[2*t], r1 = token_rows[2*t+1];
    float w0 = row_weight[r0], w1 = row_weight[r1];
    const float4 y0 = *(const float4*)&ybuf[(size_t)r0 * DM + d];
    const float4 y1 = *(const float4*)&ybuf[(size_t)r1 * DM + d];
    float4 o;
    o.x = w0*y0.x + w1*y1.x;
    o.y = w0*y0.y + w1*y1.y;
    o.z = w0*y0.z + w1*y1.z;
    o.w = w0*y0.w + w1*y1.w;
    *(float4*)&out[(size_t)t * DM + d] = o;
}

extern "C" void kernel_launch(void* const* d_in, const int* in_sizes, int n_in,
                              void* d_out, int out_size, void* d_ws, size_t ws_size,
                              hipStream_t stream) {
    const float* x  = (const float*)d_in[0];
    const float* gw = (const float*)d_in[1];
    const float* gb = (const float*)d_in[2];
    const float* w1 = (const float*)d_in[3];
    const float* b1 = (const float*)d_in[4];
    const float* w2 = (const float*)d_in[5];
    const float* b2 = (const float*)d_in[6];
    float* out = (float*)d_out;

    char* ws = (char*)d_ws;
    size_t off = 0;
    auto alloc = [&](size_t bytes) -> void* {
        void* p = ws + off; off = (off + bytes + 255) & ~(size_t)255; return p;
    };
    u16*   xb   = (u16*)alloc((size_t)T_TOK * DM * 2);
    u16*   w1t  = (u16*)alloc((size_t)NE * DM * HID * 2);
    u16*   w2t  = (u16*)alloc((size_t)NE * DM * HID * 2);
    u16*   hbuf = (u16*)alloc((size_t)RP_MAX * HID * 2);
    float* ybuf = (float*)alloc((size_t)RP_MAX * DM * 4);
    int*   tok_e = (int*)alloc(2 * T_TOK * 4);
    float* tok_w = (float*)alloc(2 * T_TOK * 4);
    int*   counts  = (int*)alloc(64);
    int*   cursors = (int*)alloc(64);
    int*   pad_off = (int*)alloc(64);
    int*   row_token  = (int*)alloc(RP_MAX * 4);
    float* row_weight = (float*)alloc(RP_MAX * 4);
    int*   token_rows = (int*)alloc(2 * T_TOK * 4);
    int*   tile_expert = (int*)alloc(MTILES * 4);

    k_zero<<<1, 64, 0, stream>>>(counts, cursors);
    k_gate<<<T_TOK/4, 256, 0, stream>>>(x, gw, gb, tok_e, tok_w, counts);
    k_scan<<<1, 256, 0, stream>>>(counts, pad_off, tile_expert, row_token);
    k_assign<<<T_TOK/256, 256, 0, stream>>>(tok_e, tok_w, pad_off, cursors, row_token, row_weight, token_rows);
    k_convx<<<(T_TOK*DM)/(256*8), 256, 0, stream>>>(x, xb);
    k_transpose<DM, HID><<<NE*(DM/64)*(HID/64), 256, 0, stream>>>(w1, w1t);
    k_transpose<HID, DM><<<NE*(DM/64)*(HID/64), 256, 0, stream>>>(w2, w2t);
    k_gemm<HID, DM, true, true><<<dim3(HID/128, MTILES), 256, 0, stream>>>(
        xb, w1t, b1, (void*)hbuf, row_token, tile_expert);
    k_gemm<DM, HID, false, false><<<dim3(DM/128, MTILES), 256, 0, stream>>>(
        hbuf, w2t, b2, (void*)ybuf, row_token, tile_expert);
    k_combine<<<T_TOK, 256, 0, stream>>>(ybuf, token_rows, row_weight, out);
}

// Round 2
// 896.158 us; speedup vs baseline: 1.0563x; 1.0563x over previous
//
#include <hip/hip_runtime.h>
#include <stdint.h>

#define T_TOK 8192
#define DM 1024
#define HID 4096
#define NE 8
#define RP_MAX 17408   // 16384 + 8*128 worst-case padded rows
#define MTILES 136     // RP_MAX / 128

typedef unsigned short u16;
typedef __attribute__((ext_vector_type(4))) float f32x4;
typedef __attribute__((ext_vector_type(8))) __bf16 bf16x8;

#define GLB(p) ((const __attribute__((address_space(1))) unsigned int*)(p))
#define LDSP(p) ((__attribute__((address_space(3))) unsigned int*)(p))

__device__ __forceinline__ u16 f2bf(float f) {
    union { float f; unsigned u; } c; c.f = f;
    unsigned r = (c.u + 0x7FFFu + ((c.u >> 16) & 1u)) >> 16;
    return (u16)r;
}

// ---------- 0: zero counters ----------
__global__ void k_zero(int* counts, int* cursors) {
    if (threadIdx.x < NE) { counts[threadIdx.x] = 0; cursors[threadIdx.x] = 0; }
}

// ---------- 1: gating (one wave per token, fp32) ----------
__global__ __launch_bounds__(256) void k_gate(const float* __restrict__ x,
        const float* __restrict__ gw, const float* __restrict__ gb,
        int* __restrict__ tok_e, float* __restrict__ tok_w, int* __restrict__ counts) {
    int t = blockIdx.x * 4 + (threadIdx.x >> 6);
    int lane = threadIdx.x & 63;
    const float* xr = x + (size_t)t * DM;
    float a0=0,a1=0,a2=0,a3=0,a4=0,a5=0,a6=0,a7=0;
    for (int d = lane; d < DM; d += 64) {
        float xv = xr[d];
        const float4* g = (const float4*)(gw + (size_t)d * NE);
        float4 g0 = g[0], g1 = g[1];
        a0 += xv*g0.x; a1 += xv*g0.y; a2 += xv*g0.z; a3 += xv*g0.w;
        a4 += xv*g1.x; a5 += xv*g1.y; a6 += xv*g1.z; a7 += xv*g1.w;
    }
    #pragma unroll
    for (int off = 32; off; off >>= 1) {
        a0 += __shfl_xor(a0, off); a1 += __shfl_xor(a1, off);
        a2 += __shfl_xor(a2, off); a3 += __shfl_xor(a3, off);
        a4 += __shfl_xor(a4, off); a5 += __shfl_xor(a5, off);
        a6 += __shfl_xor(a6, off); a7 += __shfl_xor(a7, off);
    }
    if (lane == 0) {
        float l[8] = {a0+gb[0],a1+gb[1],a2+gb[2],a3+gb[3],a4+gb[4],a5+gb[5],a6+gb[6],a7+gb[7]};
        int e0 = 0;
        #pragma unroll
        for (int e = 1; e < 8; ++e) if (l[e] > l[e0]) e0 = e;
        int e1 = (e0 == 0) ? 1 : 0;
        #pragma unroll
        for (int e = 0; e < 8; ++e) if (e != e0 && l[e] > l[e1]) e1 = e;
        // top-2 renormalized softmax: full denominator cancels
        float p1 = expf(l[e1] - l[e0]);
        float inv = 1.f / (1.f + p1);
        tok_e[2*t] = e0; tok_e[2*t+1] = e1;
        tok_w[2*t] = inv; tok_w[2*t+1] = p1 * inv;
        atomicAdd(&counts[e0], 1);
        atomicAdd(&counts[e1], 1);
    }
}

// ---------- 2: padded prefix + tile->expert map ----------
__global__ void k_scan(const int* __restrict__ counts, int* __restrict__ pad_off,
                       int* __restrict__ tile_expert, int* __restrict__ row_token) {
    __shared__ int off[NE + 1];
    if (threadIdx.x == 0) {
        int o = 0;
        for (int e = 0; e < NE; ++e) { off[e] = o; pad_off[e] = o; o += ((counts[e] + 127) >> 7) << 7; }
        off[NE] = o; pad_off[NE] = o;
    }
    __syncthreads();
    for (int i = threadIdx.x; i < MTILES; i += blockDim.x) {
        int ex = -1, base = i * 128;
        #pragma unroll
        for (int e = 0; e < NE; ++e) if (base >= off[e] && base < off[e+1]) ex = e;
        tile_expert[i] = ex;
    }
    for (int i = threadIdx.x; i < RP_MAX; i += blockDim.x) row_token[i] = -1;
}

// ---------- 3: assign rows ----------
__global__ __launch_bounds__(256) void k_assign(const int* __restrict__ tok_e, const float* __restrict__ tok_w,
        const int* __restrict__ pad_off, int* __restrict__ cursors,
        int* __restrict__ row_token, float* __restrict__ row_weight, int* __restrict__ token_rows) {
    int t = blockIdx.x * 256 + threadIdx.x;
    if (t >= T_TOK) return;
    #pragma unroll
    for (int k = 0; k < 2; ++k) {
        int e = tok_e[2*t+k];
        int pos = atomicAdd(&cursors[e], 1);
        int r = pad_off[e] + pos;
        row_token[r] = t;
        row_weight[r] = tok_w[2*t+k];
        token_rows[2*t+k] = r;
    }
}

// ---------- 4: x fp32 -> bf16 ----------
__global__ __launch_bounds__(256) void k_convx(const float* __restrict__ x, u16* __restrict__ xb) {
    size_t i = ((size_t)blockIdx.x * 256 + threadIdx.x) * 8;
    const float4* p = (const float4*)(x + i);
    float4 v0 = p[0], v1 = p[1];
    uint4 o;
    o.x = f2bf(v0.x) | ((unsigned)f2bf(v0.y) << 16);
    o.y = f2bf(v0.z) | ((unsigned)f2bf(v0.w) << 16);
    o.z = f2bf(v1.x) | ((unsigned)f2bf(v1.y) << 16);
    o.w = f2bf(v1.z) | ((unsigned)f2bf(v1.w) << 16);
    *(uint4*)(xb + i) = o;
}

// ---------- 5: weight transpose+convert: [E][R][C] f32 -> [E][C][R] bf16 ----------
template<int R, int C>
__global__ __launch_bounds__(256) void k_transpose(const float* __restrict__ in, u16* __restrict__ out) {
    __shared__ u16 lds[64][65];
    const int TC = C / 64;
    const int tiles = (R / 64) * TC;
    int e = blockIdx.x / tiles;
    int rem = blockIdx.x % tiles;
    int rt = rem / TC, ct = rem % TC;
    const float* src = in + (size_t)e * R * C;
    u16* dst = out + (size_t)e * R * C;
    int rl = threadIdx.x >> 4;
    int cl = (threadIdx.x & 15) * 4;
    #pragma unroll
    for (int i = 0; i < 4; ++i) {
        int r = rl + i * 16;
        float4 v = *(const float4*)&src[(size_t)(rt*64 + r) * C + ct*64 + cl];
        lds[r][cl+0] = f2bf(v.x); lds[r][cl+1] = f2bf(v.y);
        lds[r][cl+2] = f2bf(v.z); lds[r][cl+3] = f2bf(v.w);
    }
    __syncthreads();
    #pragma unroll
    for (int i = 0; i < 4; ++i) {
        int ro = rl + i * 16;
        ushort4 o;
        o.x = lds[cl+0][ro]; o.y = lds[cl+1][ro];
        o.z = lds[cl+2][ro]; o.w = lds[cl+3][ro];
        *(ushort4*)&dst[(size_t)(ct*64 + ro) * R + rt*64 + cl] = o;
    }
}

// ---------- 6: MoE GEMM (128x128 tile, BK=64, 4 waves, 16x16x32 bf16 MFMA) ----------
// T1: XCD-chunked block swizzle (flat grid, divisible by 8).
// T2: LDS XOR swizzle, both-sides: global source k-slot pre-swizzled by
//     (lane>>3) == row&7 (gload_lds dest stays linear); fragment reads XOR
//     the same involution: slot' = kslot ^ (row&7).
template<int NBN, int N, int K, bool GATHER, bool SILU>
__global__ __launch_bounds__(256) void k_gemm(
    const u16* __restrict__ Asrc, const u16* __restrict__ Bw,
    const float* __restrict__ bias, void* __restrict__ Out,
    const int* __restrict__ row_token, const int* __restrict__ tile_expert)
{
    // XCD-chunked swizzle: blocks with original id ≡ k (mod 8) run on XCD k;
    // map them to a contiguous sid chunk so same-bm blocks share one L2.
    int id = blockIdx.x;
    int cpx = (NBN * MTILES) >> 3;
    int sid = (id & 7) * cpx + (id >> 3);
    int bm = sid / NBN;
    int bn = sid % NBN;

    int e = tile_expert[bm];
    if (e < 0) return;
    int tid = threadIdx.x, wid = tid >> 6, lane = tid & 63;

    __shared__ u16 Al[128 * 64];
    __shared__ u16 Bl[128 * 64];

    // staging: inst i of wave wid covers rows (wid*4+i)*8 + (lane>>3);
    // global k-slot is PRE-SWIZZLED: ((lane&7) ^ (lane>>3)) so that the linear
    // LDS write lands data for k-slot g at LDS slot g ^ (row&7).
    const u16* ap[4];
    const u16* bp[4];
    int ksl = ((lane & 7) ^ (lane >> 3)) * 8;
    #pragma unroll
    for (int i = 0; i < 4; ++i) {
        int row = (wid * 4 + i) * 8 + (lane >> 3);
        size_t arow;
        if (GATHER) {
            int tk = row_token[bm * 128 + row];
            if (tk < 0) tk = 0;              // pad rows compute duplicate of token 0 (ignored)
            arow = (size_t)tk * K;
        } else {
            arow = (size_t)(bm * 128 + row) * K;
        }
        ap[i] = Asrc + arow + ksl;
        bp[i] = Bw + (size_t)e * N * K + (size_t)(bn * 128 + row) * K + ksl;
    }

    f32x4 acc[4][4];
    #pragma unroll
    for (int i = 0; i < 4; ++i)
        #pragma unroll
        for (int j = 0; j < 4; ++j) acc[i][j] = f32x4{0.f, 0.f, 0.f, 0.f};

    int wr = wid >> 1, wc = wid & 1;

    for (int kt = 0; kt < K / 64; ++kt) {
        #pragma unroll
        for (int i = 0; i < 4; ++i) {
            __builtin_amdgcn_global_load_lds(GLB(ap[i] + kt * 64), LDSP(&Al[(wid*4+i)*512]), 16, 0, 0);
            __builtin_amdgcn_global_load_lds(GLB(bp[i] + kt * 64), LDSP(&Bl[(wid*4+i)*512]), 16, 0, 0);
        }
        asm volatile("s_waitcnt vmcnt(0)" ::: "memory");
        __syncthreads();
        #pragma unroll
        for (int s = 0; s < 2; ++s) {
            // swizzled read slot: (kslot) ^ (row&7); row&7 == lane&7 for all fragments
            int sl = (((s * 4) + (lane >> 4)) ^ (lane & 7)) << 4;
            bf16x8 af[4], bfr[4];
            #pragma unroll
            for (int i = 0; i < 4; ++i) {
                int ar = wr * 64 + i * 16 + (lane & 15);
                af[i] = *(const bf16x8*)((const char*)Al + ar * 128 + sl);
            }
            #pragma unroll
            for (int j = 0; j < 4; ++j) {
                int br = wc * 64 + j * 16 + (lane & 15);
                bfr[j] = *(const bf16x8*)((const char*)Bl + br * 128 + sl);
            }
            #pragma unroll
            for (int i = 0; i < 4; ++i)
                #pragma unroll
                for (int j = 0; j < 4; ++j)
                    acc[i][j] = __builtin_amdgcn_mfma_f32_16x16x32_bf16(af[i], bfr[j], acc[i][j], 0, 0, 0);
        }
        __syncthreads();
    }

    // epilogue: C row = (lane>>4)*4 + reg, col = lane&15 (verified gfx950 C/D layout)
    int rbase = bm * 128 + wr * 64 + (lane >> 4) * 4;
    int cbase = bn * 128 + wc * 64 + (lane & 15);
    #pragma unroll
    for (int j = 0; j < 4; ++j) {
        int col = cbase + j * 16;
        float bv = bias[e * N + col];
        #pragma unroll
        for (int i = 0; i < 4; ++i) {
            #pragma unroll
            for (int r = 0; r < 4; ++r) {
                int row = rbase + i * 16 + r;
                float v = acc[i][j][r] + bv;
                if (SILU) {
                    v = v / (1.f + __expf(-v));
                    ((u16*)Out)[(size_t)row * N + col] = f2bf(v);
                } else {
                    ((float*)Out)[(size_t)row * N + col] = v;
                }
            }
        }
    }
}

// ---------- 7: combine (one block per token, float4) ----------
__global__ __launch_bounds__(256) void k_combine(const float* __restrict__ ybuf,
        const int* __restrict__ token_rows, const float* __restrict__ row_weight,
        float* __restrict__ out) {
    int t = blockIdx.x;
    int d = threadIdx.x * 4;
    int r0 = token_rows[2*t], r1 = token_rows[2*t+1];
    float w0 = row_weight[r0], w1 = row_weight[r1];
    const float4 y0 = *(const float4*)&ybuf[(size_t)r0 * DM + d];
    const float4 y1 = *(const float4*)&ybuf[(size_t)r1 * DM + d];
    float4 o;
    o.x = w0*y0.x + w1*y1.x;
    o.y = w0*y0.y + w1*y1.y;
    o.z = w0*y0.z + w1*y1.z;
    o.w = w0*y0.w + w1*y1.w;
    *(float4*)&out[(size_t)t * DM + d] = o;
}

extern "C" void kernel_launch(void* const* d_in, const int* in_sizes, int n_in,
                              void* d_out, int out_size, void* d_ws, size_t ws_size,
                              hipStream_t stream) {
    const float* x  = (const float*)d_in[0];
    const float* gw = (const float*)d_in[1];
    const float* gb = (const float*)d_in[2];
    const float* w1 = (const float*)d_in[3];
    const float* b1 = (const float*)d_in[4];
    const float* w2 = (const float*)d_in[5];
    const float* b2 = (const float*)d_in[6];
    float* out = (float*)d_out;

    char* ws = (char*)d_ws;
    size_t off = 0;
    auto alloc = [&](size_t bytes) -> void* {
        void* p = ws + off; off = (off + bytes + 255) & ~(size_t)255; return p;
    };
    u16*   xb   = (u16*)alloc((size_t)T_TOK * DM * 2);
    u16*   w1t  = (u16*)alloc((size_t)NE * DM * HID * 2);
    u16*   w2t  = (u16*)alloc((size_t)NE * DM * HID * 2);
    u16*   hbuf = (u16*)alloc((size_t)RP_MAX * HID * 2);
    float* ybuf = (float*)alloc((size_t)RP_MAX * DM * 4);
    int*   tok_e = (int*)alloc(2 * T_TOK * 4);
    float* tok_w = (float*)alloc(2 * T_TOK * 4);
    int*   counts  = (int*)alloc(64);
    int*   cursors = (int*)alloc(64);
    int*   pad_off = (int*)alloc(64);
    int*   row_token  = (int*)alloc(RP_MAX * 4);
    float* row_weight = (float*)alloc(RP_MAX * 4);
    int*   token_rows = (int*)alloc(2 * T_TOK * 4);
    int*   tile_expert = (int*)alloc(MTILES * 4);

    k_zero<<<1, 64, 0, stream>>>(counts, cursors);
    k_gate<<<T_TOK/4, 256, 0, stream>>>(x, gw, gb, tok_e, tok_w, counts);
    k_scan<<<1, 256, 0, stream>>>(counts, pad_off, tile_expert, row_token);
    k_assign<<<T_TOK/256, 256, 0, stream>>>(tok_e, tok_w, pad_off, cursors, row_token, row_weight, token_rows);
    k_convx<<<(T_TOK*DM)/(256*8), 256, 0, stream>>>(x, xb);
    k_transpose<DM, HID><<<NE*(DM/64)*(HID/64), 256, 0, stream>>>(w1, w1t);
    k_transpose<HID, DM><<<NE*(DM/64)*(HID/64), 256, 0, stream>>>(w2, w2t);
    k_gemm<HID/128, HID, DM, true, true><<<dim3((HID/128)*MTILES), 256, 0, stream>>>(
        xb, w1t, b1, (void*)hbuf, row_token, tile_expert);
    k_gemm<DM/128, DM, HID, false, false><<<dim3((DM/128)*MTILES), 256, 0, stream>>>(
        hbuf, w2t, b2, (void*)ybuf, row_token, tile_expert);
    k_combine<<<T_TOK, 256, 0, stream>>>(ybuf, token_rows, row_weight, out);
}

// Round 3
// 891.651 us; speedup vs baseline: 1.0616x; 1.0051x over previous
//
#include <hip/hip_runtime.h>
#include <stdint.h>

#define T_TOK 8192
#define DM 1024
#define HID 4096
#define NE 8
#define RP2 18432      // 16384 + 8*256 worst-case rows padded to 256
#define MT128 144      // RP2 / 128
#define MT256 72       // RP2 / 256

typedef unsigned short u16;
typedef __attribute__((ext_vector_type(4))) float f32x4;
typedef __attribute__((ext_vector_type(8))) __bf16 bf16x8;

#define GLB(p) ((const __attribute__((address_space(1))) unsigned int*)(p))
#define LDSP(p) ((__attribute__((address_space(3))) unsigned int*)(p))

__device__ __forceinline__ u16 f2bf(float f) {
    union { float f; unsigned u; } c; c.f = f;
    unsigned r = (c.u + 0x7FFFu + ((c.u >> 16) & 1u)) >> 16;
    return (u16)r;
}

// ---------- 0: zero counters ----------
__global__ void k_zero(int* counts, int* cursors) {
    if (threadIdx.x < NE) { counts[threadIdx.x] = 0; cursors[threadIdx.x] = 0; }
}

// ---------- 1: gating (one wave per token, fp32) ----------
__global__ __launch_bounds__(256) void k_gate(const float* __restrict__ x,
        const float* __restrict__ gw, const float* __restrict__ gb,
        int* __restrict__ tok_e, float* __restrict__ tok_w, int* __restrict__ counts) {
    int t = blockIdx.x * 4 + (threadIdx.x >> 6);
    int lane = threadIdx.x & 63;
    const float* xr = x + (size_t)t * DM;
    float a0=0,a1=0,a2=0,a3=0,a4=0,a5=0,a6=0,a7=0;
    for (int d = lane; d < DM; d += 64) {
        float xv = xr[d];
        const float4* g = (const float4*)(gw + (size_t)d * NE);
        float4 g0 = g[0], g1 = g[1];
        a0 += xv*g0.x; a1 += xv*g0.y; a2 += xv*g0.z; a3 += xv*g0.w;
        a4 += xv*g1.x; a5 += xv*g1.y; a6 += xv*g1.z; a7 += xv*g1.w;
    }
    #pragma unroll
    for (int off = 32; off; off >>= 1) {
        a0 += __shfl_xor(a0, off); a1 += __shfl_xor(a1, off);
        a2 += __shfl_xor(a2, off); a3 += __shfl_xor(a3, off);
        a4 += __shfl_xor(a4, off); a5 += __shfl_xor(a5, off);
        a6 += __shfl_xor(a6, off); a7 += __shfl_xor(a7, off);
    }
    if (lane == 0) {
        float l[8] = {a0+gb[0],a1+gb[1],a2+gb[2],a3+gb[3],a4+gb[4],a5+gb[5],a6+gb[6],a7+gb[7]};
        int e0 = 0;
        #pragma unroll
        for (int e = 1; e < 8; ++e) if (l[e] > l[e0]) e0 = e;
        int e1 = (e0 == 0) ? 1 : 0;
        #pragma unroll
        for (int e = 0; e < 8; ++e) if (e != e0 && l[e] > l[e1]) e1 = e;
        float p1 = expf(l[e1] - l[e0]);
        float inv = 1.f / (1.f + p1);
        tok_e[2*t] = e0; tok_e[2*t+1] = e1;
        tok_w[2*t] = inv; tok_w[2*t+1] = p1 * inv;
        atomicAdd(&counts[e0], 1);
        atomicAdd(&counts[e1], 1);
    }
}

// ---------- 2: padded prefix (256-aligned) + tile->expert map (128-granular) ----------
__global__ void k_scan(const int* __restrict__ counts, int* __restrict__ pad_off,
                       int* __restrict__ tile_expert, int* __restrict__ row_token) {
    __shared__ int off[NE + 1];
    if (threadIdx.x == 0) {
        int o = 0;
        for (int e = 0; e < NE; ++e) { off[e] = o; pad_off[e] = o; o += ((counts[e] + 255) >> 8) << 8; }
        off[NE] = o; pad_off[NE] = o;
    }
    __syncthreads();
    for (int i = threadIdx.x; i < MT128; i += blockDim.x) {
        int ex = -1, base = i * 128;
        #pragma unroll
        for (int e = 0; e < NE; ++e) if (base >= off[e] && base < off[e+1]) ex = e;
        tile_expert[i] = ex;
    }
    for (int i = threadIdx.x; i < RP2; i += blockDim.x) row_token[i] = -1;
}

// ---------- 3: assign rows ----------
__global__ __launch_bounds__(256) void k_assign(const int* __restrict__ tok_e, const float* __restrict__ tok_w,
        const int* __restrict__ pad_off, int* __restrict__ cursors,
        int* __restrict__ row_token, float* __restrict__ row_weight, int* __restrict__ token_rows) {
    int t = blockIdx.x * 256 + threadIdx.x;
    if (t >= T_TOK) return;
    #pragma unroll
    for (int k = 0; k < 2; ++k) {
        int e = tok_e[2*t+k];
        int pos = atomicAdd(&cursors[e], 1);
        int r = pad_off[e] + pos;
        row_token[r] = t;
        row_weight[r] = tok_w[2*t+k];
        token_rows[2*t+k] = r;
    }
}

// ---------- 4: x fp32 -> bf16 ----------
__global__ __launch_bounds__(256) void k_convx(const float* __restrict__ x, u16* __restrict__ xb) {
    size_t i = ((size_t)blockIdx.x * 256 + threadIdx.x) * 8;
    const float4* p = (const float4*)(x + i);
    float4 v0 = p[0], v1 = p[1];
    uint4 o;
    o.x = f2bf(v0.x) | ((unsigned)f2bf(v0.y) << 16);
    o.y = f2bf(v0.z) | ((unsigned)f2bf(v0.w) << 16);
    o.z = f2bf(v1.x) | ((unsigned)f2bf(v1.y) << 16);
    o.w = f2bf(v1.z) | ((unsigned)f2bf(v1.w) << 16);
    *(uint4*)(xb + i) = o;
}

// ---------- 5: weight transpose+convert: [E][R][C] f32 -> [E][C][R] bf16 ----------
// 256R x 64C tile; float4 reads (256B runs), ushort4 writes (512B runs).
// LDS [64][260]: write side 2-way (free), read side sequential words.
template<int R, int C>
__global__ __launch_bounds__(256) void k_transpose(const float* __restrict__ in, u16* __restrict__ out) {
    __shared__ u16 lds[64][260];
    const int TR = R / 256, TC = C / 64;
    const int tiles = TR * TC;
    int e = blockIdx.x / tiles;
    int rem = blockIdx.x % tiles;
    int rt = rem / TC, ct = rem % TC;
    const float* src = in + (size_t)e * R * C + (size_t)rt * 256 * C + ct * 64;
    u16* dst = out + (size_t)e * R * C + (size_t)ct * 64 * R + rt * 256;
    int t = threadIdx.x;
    #pragma unroll
    for (int i = 0; i < 16; ++i) {
        int o = i * 256 + t;
        int r = o >> 4;
        int c4 = (o & 15) * 4;
        float4 v = *(const float4*)&src[(size_t)r * C + c4];
        lds[c4+0][r] = f2bf(v.x);
        lds[c4+1][r] = f2bf(v.y);
        lds[c4+2][r] = f2bf(v.z);
        lds[c4+3][r] = f2bf(v.w);
    }
    __syncthreads();
    #pragma unroll
    for (int i = 0; i < 16; ++i) {
        int o = i * 256 + t;
        int c = o >> 6;
        int r4 = (o & 63) * 4;
        ushort4 u;
        u.x = lds[c][r4+0]; u.y = lds[c][r4+1];
        u.z = lds[c][r4+2]; u.w = lds[c][r4+3];
        *(ushort4*)&dst[(size_t)c * R + r4] = u;
    }
}

// ---------- 6a: 256x256 8-wave double-buffered GEMM (GEMM1) ----------
// T1 XCD swizzle + T2 both-sides XOR swizzle + T3-min (prefetch next tile
// before compute, single vmcnt(0)+barrier per K-tile) + T5 setprio.
template<int NBN, int N, int K, bool GATHER, bool SILU>
__global__ __launch_bounds__(512, 2) void k_gemm256(
    const u16* __restrict__ Asrc, const u16* __restrict__ Bw,
    const float* __restrict__ bias, void* __restrict__ Out,
    const int* __restrict__ row_token, const int* __restrict__ tile_expert, int mt)
{
    int id = blockIdx.x;
    int cpx = (NBN * mt) >> 3;
    int sid = (id & 7) * cpx + (id >> 3);
    int bm = sid / NBN, bn = sid % NBN;
    int e = tile_expert[2 * bm];           // 256-pad => both 128-halves same expert
    if (e < 0) return;
    int tid = threadIdx.x, wid = tid >> 6, lane = tid & 63;
    int wr = wid >> 2, wc = wid & 3;

    __shared__ u16 Al[2 * 256 * 64];
    __shared__ u16 Bl[2 * 256 * 64];

    // per-lane byte offsets for staging (k-slot pre-swizzled by row&7)
    unsigned kslb = ((unsigned)((lane & 7) ^ (lane >> 3))) * 16u;
    unsigned aoff[4], boff[4];
    #pragma unroll
    for (int i = 0; i < 4; ++i) {
        int row = (wid * 4 + i) * 8 + (lane >> 3);
        unsigned arow;
        if (GATHER) {
            int tk = row_token[bm * 256 + row];
            if (tk < 0) tk = 0;            // pad rows: duplicate token 0 (ignored)
            arow = (unsigned)tk;
        } else {
            arow = (unsigned)(bm * 256 + row);
        }
        aoff[i] = arow * (unsigned)(K * 2) + kslb;
        boff[i] = ((unsigned)e * (unsigned)N + (unsigned)(bn * 256 + row)) * (unsigned)(K * 2) + kslb;
    }

    f32x4 acc[8][4];
    #pragma unroll
    for (int m = 0; m < 8; ++m)
        #pragma unroll
        for (int n = 0; n < 4; ++n) acc[m][n] = f32x4{0.f, 0.f, 0.f, 0.f};

    auto stage = [&](int buf, int kt) {
        unsigned ko = (unsigned)kt * 128u;
        #pragma unroll
        for (int i = 0; i < 4; ++i) {
            __builtin_amdgcn_global_load_lds(GLB((const char*)Asrc + aoff[i] + ko),
                LDSP(&Al[buf * 16384 + (wid * 4 + i) * 512]), 16, 0, 0);
            __builtin_amdgcn_global_load_lds(GLB((const char*)Bw + boff[i] + ko),
                LDSP(&Bl[buf * 16384 + (wid * 4 + i) * 512]), 16, 0, 0);
        }
    };

    auto compute = [&](int buf) {
        const char* Ab = (const char*)&Al[buf * 16384];
        const char* Bb = (const char*)&Bl[buf * 16384];
        unsigned sl0 = (unsigned)(((lane >> 4) ^ (lane & 7)) << 4);
        unsigned sl1 = (unsigned)((((lane >> 4) + 4) ^ (lane & 7)) << 4);
        bf16x8 bfr[4][2];
        #pragma unroll
        for (int n = 0; n < 4; ++n) {
            unsigned br = (unsigned)(wc * 64 + n * 16 + (lane & 15)) * 128u;
            bfr[n][0] = *(const bf16x8*)(Bb + br + sl0);
            bfr[n][1] = *(const bf16x8*)(Bb + br + sl1);
        }
        __builtin_amdgcn_s_setprio(1);
        #pragma unroll
        for (int m = 0; m < 8; ++m) {
            unsigned ar = (unsigned)(wr * 128 + m * 16 + (lane & 15)) * 128u;
            bf16x8 a0 = *(const bf16x8*)(Ab + ar + sl0);
            bf16x8 a1 = *(const bf16x8*)(Ab + ar + sl1);
            #pragma unroll
            for (int n = 0; n < 4; ++n) {
                acc[m][n] = __builtin_amdgcn_mfma_f32_16x16x32_bf16(a0, bfr[n][0], acc[m][n], 0, 0, 0);
                acc[m][n] = __builtin_amdgcn_mfma_f32_16x16x32_bf16(a1, bfr[n][1], acc[m][n], 0, 0, 0);
            }
        }
        __builtin_amdgcn_s_setprio(0);
    };

    stage(0, 0);
    asm volatile("s_waitcnt vmcnt(0)" ::: "memory");
    __syncthreads();
    int cur = 0;
    const int NT = K / 64;
    for (int kt = 1; kt < NT; ++kt) {
        stage(cur ^ 1, kt);                 // issue next-tile loads BEFORE compute
        compute(cur);                       // ds_read drained by lgkmcnt before MFMA
        asm volatile("s_waitcnt vmcnt(0)" ::: "memory");
        __syncthreads();                    // one barrier per K-tile
        cur ^= 1;
    }
    compute(cur);

    // epilogue: C row=(lane>>4)*4+reg, col=lane&15
    int rb = bm * 256 + wr * 128 + (lane >> 4) * 4;
    int cb = bn * 256 + wc * 64 + (lane & 15);
    #pragma unroll
    for (int n = 0; n < 4; ++n) {
        int col = cb + n * 16;
        float bv = bias[e * N + col];
        #pragma unroll
        for (int m = 0; m < 8; ++m) {
            #pragma unroll
            for (int r = 0; r < 4; ++r) {
                int row = rb + m * 16 + r;
                float v = acc[m][n][r] + bv;
                if (SILU) {
                    v = v / (1.f + __expf(-v));
                    ((u16*)Out)[(size_t)row * N + col] = f2bf(v);
                } else {
                    ((float*)Out)[(size_t)row * N + col] = v;
                }
            }
        }
    }
}

// ---------- 6b: 128x128 4-wave GEMM (GEMM2) ----------
template<int NBN, int N, int K, bool GATHER, bool SILU>
__global__ __launch_bounds__(256) void k_gemm128(
    const u16* __restrict__ Asrc, const u16* __restrict__ Bw,
    const float* __restrict__ bias, void* __restrict__ Out,
    const int* __restrict__ row_token, const int* __restrict__ tile_expert, int mt)
{
    int id = blockIdx.x;
    int cpx = (NBN * mt) >> 3;
    int sid = (id & 7) * cpx + (id >> 3);
    int bm = sid / NBN;
    int bn = sid % NBN;

    int e = tile_expert[bm];
    if (e < 0) return;
    int tid = threadIdx.x, wid = tid >> 6, lane = tid & 63;

    __shared__ u16 Al[128 * 64];
    __shared__ u16 Bl[128 * 64];

    const u16* ap[4];
    const u16* bp[4];
    int ksl = ((lane & 7) ^ (lane >> 3)) * 8;
    #pragma unroll
    for (int i = 0; i < 4; ++i) {
        int row = (wid * 4 + i) * 8 + (lane >> 3);
        size_t arow;
        if (GATHER) {
            int tk = row_token[bm * 128 + row];
            if (tk < 0) tk = 0;
            arow = (size_t)tk * K;
        } else {
            arow = (size_t)(bm * 128 + row) * K;
        }
        ap[i] = Asrc + arow + ksl;
        bp[i] = Bw + (size_t)e * N * K + (size_t)(bn * 128 + row) * K + ksl;
    }

    f32x4 acc[4][4];
    #pragma unroll
    for (int i = 0; i < 4; ++i)
        #pragma unroll
        for (int j = 0; j < 4; ++j) acc[i][j] = f32x4{0.f, 0.f, 0.f, 0.f};

    int wr = wid >> 1, wc = wid & 1;

    for (int kt = 0; kt < K / 64; ++kt) {
        #pragma unroll
        for (int i = 0; i < 4; ++i) {
            __builtin_amdgcn_global_load_lds(GLB(ap[i] + kt * 64), LDSP(&Al[(wid*4+i)*512]), 16, 0, 0);
            __builtin_amdgcn_global_load_lds(GLB(bp[i] + kt * 64), LDSP(&Bl[(wid*4+i)*512]), 16, 0, 0);
        }
        asm volatile("s_waitcnt vmcnt(0)" ::: "memory");
        __syncthreads();
        #pragma unroll
        for (int s = 0; s < 2; ++s) {
            int sl = (((s * 4) + (lane >> 4)) ^ (lane & 7)) << 4;
            bf16x8 af[4], bfr[4];
            #pragma unroll
            for (int i = 0; i < 4; ++i) {
                int ar = wr * 64 + i * 16 + (lane & 15);
                af[i] = *(const bf16x8*)((const char*)Al + ar * 128 + sl);
            }
            #pragma unroll
            for (int j = 0; j < 4; ++j) {
                int br = wc * 64 + j * 16 + (lane & 15);
                bfr[j] = *(const bf16x8*)((const char*)Bl + br * 128 + sl);
            }
            #pragma unroll
            for (int i = 0; i < 4; ++i)
                #pragma unroll
                for (int j = 0; j < 4; ++j)
                    acc[i][j] = __builtin_amdgcn_mfma_f32_16x16x32_bf16(af[i], bfr[j], acc[i][j], 0, 0, 0);
        }
        __syncthreads();
    }

    int rbase = bm * 128 + wr * 64 + (lane >> 4) * 4;
    int cbase = bn * 128 + wc * 64 + (lane & 15);
    #pragma unroll
    for (int j = 0; j < 4; ++j) {
        int col = cbase + j * 16;
        float bv = bias[e * N + col];
        #pragma unroll
        for (int i = 0; i < 4; ++i) {
            #pragma unroll
            for (int r = 0; r < 4; ++r) {
                int row = rbase + i * 16 + r;
                float v = acc[i][j][r] + bv;
                if (SILU) {
                    v = v / (1.f + __expf(-v));
                    ((u16*)Out)[(size_t)row * N + col] = f2bf(v);
                } else {
                    ((float*)Out)[(size_t)row * N + col] = v;
                }
            }
        }
    }
}

// ---------- 7: combine (one block per token, float4) ----------
__global__ __launch_bounds__(256) void k_combine(const float* __restrict__ ybuf,
        const int* __restrict__ token_rows, const float* __restrict__ row_weight,
        float* __restrict__ out) {
    int t = blockIdx.x;
    int d = threadIdx.x * 4;
    int r0 = token_rows[2*t], r1 = token_rows[2*t+1];
    float w0 = row_weight[r0], w1 = row_weight[r1];
    const float4 y0 = *(const float4*)&ybuf[(size_t)r0 * DM + d];
    const float4 y1 = *(const float4*)&ybuf[(size_t)r1 * DM + d];
    float4 o;
    o.x = w0*y0.x + w1*y1.x;
    o.y = w0*y0.y + w1*y1.y;
    o.z = w0*y0.z + w1*y1.z;
    o.w = w0*y0.w + w1*y1.w;
    *(float4*)&out[(size_t)t * DM + d] = o;
}

extern "C" void kernel_launch(void* const* d_in, const int* in_sizes, int n_in,
                              void* d_out, int out_size, void* d_ws, size_t ws_size,
                              hipStream_t stream) {
    const float* x  = (const float*)d_in[0];
    const float* gw = (const float*)d_in[1];
    const float* gb = (const float*)d_in[2];
    const float* w1 = (const float*)d_in[3];
    const float* b1 = (const float*)d_in[4];
    const float* w2 = (const float*)d_in[5];
    const float* b2 = (const float*)d_in[6];
    float* out = (float*)d_out;

    char* ws = (char*)d_ws;
    size_t off = 0;
    auto alloc = [&](size_t bytes) -> void* {
        void* p = ws + off; off = (off + bytes + 255) & ~(size_t)255; return p;
    };
    // Order matters: ybuf (written by GEMM2) aliases w1t+xb, which are dead
    // after GEMM1 completes (stream-ordered).
    u16*   w1t  = (u16*)alloc((size_t)NE * DM * HID * 2);   // 67.1 MB
    u16*   xb   = (u16*)alloc((size_t)T_TOK * DM * 2);      // 16.8 MB
    u16*   w2t  = (u16*)alloc((size_t)NE * DM * HID * 2);   // 67.1 MB
    u16*   hbuf = (u16*)alloc((size_t)RP2 * HID * 2);       // 151 MB
    int*   tok_e = (int*)alloc(2 * T_TOK * 4);
    float* tok_w = (float*)alloc(2 * T_TOK * 4);
    int*   counts  = (int*)alloc(64);
    int*   cursors = (int*)alloc(64);
    int*   pad_off = (int*)alloc(64);
    int*   row_token  = (int*)alloc(RP2 * 4);
    float* row_weight = (float*)alloc(RP2 * 4);
    int*   token_rows = (int*)alloc(2 * T_TOK * 4);
    int*   tile_expert = (int*)alloc(MT128 * 4);
    float* ybuf = (float*)w1t;                              // 75.5 MB alias

    k_zero<<<1, 64, 0, stream>>>(counts, cursors);
    k_gate<<<T_TOK/4, 256, 0, stream>>>(x, gw, gb, tok_e, tok_w, counts);
    k_scan<<<1, 256, 0, stream>>>(counts, pad_off, tile_expert, row_token);
    k_assign<<<T_TOK/256, 256, 0, stream>>>(tok_e, tok_w, pad_off, cursors, row_token, row_weight, token_rows);
    k_convx<<<(T_TOK*DM)/(256*8), 256, 0, stream>>>(x, xb);
    k_transpose<DM, HID><<<NE*(DM/256)*(HID/64), 256, 0, stream>>>(w1, w1t);
    k_transpose<HID, DM><<<NE*(HID/256)*(DM/64), 256, 0, stream>>>(w2, w2t);
    k_gemm256<HID/256, HID, DM, true, true><<<(HID/256)*MT256, 512, 0, stream>>>(
        xb, w1t, b1, (void*)hbuf, row_token, tile_expert, MT256);
    k_gemm128<DM/128, DM, HID, false, false><<<(DM/128)*MT128, 256, 0, stream>>>(
        hbuf, w2t, b2, (void*)ybuf, row_token, tile_expert, MT128);
    k_combine<<<T_TOK, 256, 0, stream>>>(ybuf, token_rows, row_weight, out);
}